// Round 19
// baseline (82.139 us; speedup 1.0000x reference)
//
#include <hip/hip_runtime.h>
#include <hip/hip_bf16.h>

typedef __attribute__((ext_vector_type(8))) short bf16x8;
typedef __attribute__((ext_vector_type(4))) float f32x4;

__device__ __forceinline__ short f2b(float f) {
    __hip_bfloat16 h = __float2bfloat16(f);   // RNE
    return __builtin_bit_cast(short, h);
}

#define NSP 16
#define KCS 256     // floats per row per superphase (1 KB contiguous run)

// Kernel 1: x f32 -> bf16, and y2 = 2*(x @ A^T) as bf16.
__global__ void prep_kernel(const float* __restrict__ x,
                            const float* __restrict__ A,
                            ushort* __restrict__ xb,     // [64][4096] bf16
                            ushort* __restrict__ yb) {   // [64][64] bf16
    const int tid = threadIdx.x, bid = blockIdx.x;

    const int gid = bid * 256 + tid;
    if (gid < 65536) {
        float4 v = ((const float4*)x)[gid];
        ushort4 s;
        s.x = (ushort)f2b(v.x); s.y = (ushort)f2b(v.y);
        s.z = (ushort)f2b(v.z); s.w = (ushort)f2b(v.w);
        ((ushort4*)xb)[gid] = s;
    }

    const int wave = tid >> 6, lane = tid & 63;
    const int idx = bid * 4 + wave;          // 0..4095
    const int t = idx >> 6, r = idx & 63;
    const float4* xr = (const float4*)(x + (size_t)t * 4096);
    const float4* ar = (const float4*)(A + (size_t)r * 4096);
    float s = 0.f;
    #pragma unroll
    for (int i = 0; i < 16; ++i) {
        float4 a = xr[i * 64 + lane];
        float4 b = ar[i * 64 + lane];
        s += a.x * b.x + a.y * b.y + a.z * b.z + a.w * b.w;
    }
    #pragma unroll
    for (int off = 32; off; off >>= 1) s += __shfl_xor(s, off, 64);
    if (lane == 0) yb[idx] = (ushort)f2b(2.0f * s);
}

// Kernel 2: out[64][16384] = x@W^T + y2@B^T.
// 256 blocks x 512 threads (1 block/CU). R17's schedule+rotation (proven
// 58.6 us) with staging regrouped into SUPERPHASES: 2 x 64 KB LDS buffers,
// 16 superphases of 1 KB/row -- each gload_lds covers ONE row's 1 KB
// CONTIGUOUSLY, doubling the DRAM run length vs R17's 512 B (the last
// un-tested variable vs the 6.6 TB/s wread probe, whose runs were 64 KB).
// Depth unchanged: superphase i+1's 16 loads are in flight during all of
// i's consumption (~3.2 us of cover, never drained hot; the final
// vmcnt(0) hits loads issued 2 superphases earlier = free).
// Barriers: 2 per superphase (ready + end), 32 total, both roles.
__global__ void __launch_bounds__(512)
lora_gemm(const float* __restrict__ W,      // [16384][4096]
          const float* __restrict__ Bm,     // [16384][64]
          const ushort* __restrict__ xb,    // [64][4096] bf16
          const ushort* __restrict__ yb,    // [64][64] bf16
          float* __restrict__ out) {        // [64][16384]
    __shared__ char buf[2][64 * 1024];      // 2 x 64 KB f32 superpanels

    const int tid  = threadIdx.x;
    const int w    = tid >> 6;              // wave 0..7
    const int lane = tid & 63;
    const int j0   = blockIdx.x << 6;       // 64 W-rows / out-cols per block
    const int p0   = blockIdx.x & 15;       // superphase rotation start

    if (w >= 4) {
        // ------- STREAMER (waves 4..7): rows s16 .. s16+15 ---------------
        const int s16 = (w - 4) * 16;
        // issue slot i: superphase (p0+i)&15 -> buf[i&1].
        // One gload_lds per row: 1 KB contiguous dst, source pre-swizzled
        // (XOR within 128 B window; q&7 == k&7 since s16 is a mult of 16).
        auto issue = [&](int i) {
            const int sp = (p0 + i) & 15;
            char* dst = &buf[i & 1][0];
            #pragma unroll
            for (int k = 0; k < 16; ++k) {
                const int q = s16 + k;
                const char* src = (const char*)(W + (size_t)(j0 + q) * 4096
                                                + (size_t)sp * KCS)
                                  + ((lane * 16) ^ ((k & 7) << 4));
                __builtin_amdgcn_global_load_lds(
                    (const uint32_t*)src,
                    (uint32_t*)(dst + q * 1024), 16, 0, 0);
            }
        };

        issue(0);
        issue(1);
        for (int i = 0; i < NSP; ++i) {
            if (i + 1 < NSP) {
                asm volatile("s_waitcnt vmcnt(16)" ::: "memory");
            } else {
                asm volatile("s_waitcnt vmcnt(0)" ::: "memory");  // free: old
            }
            __builtin_amdgcn_s_barrier();    // ready i
            __builtin_amdgcn_s_barrier();    // end i (consumers computed)
            if (i + 2 < NSP) issue(i + 2);   // into just-freed buf[i&1]
        }
        return;
    }

    // ------- CONSUMER (waves 0..3): tokens w*16..w*16+15 -----------------
    const int c  = lane & 15;               // token row / D-col index
    const int kg = lane >> 4;               // k-group, offset kg*8
    const ushort* xrow = xb + (size_t)(w * 16 + c) * 4096 + kg * 8;

    f32x4 acc[4];
    #pragma unroll
    for (int n = 0; n < 4; ++n) acc[n] = f32x4{0.f, 0.f, 0.f, 0.f};

    for (int i = 0; i < NSP; ++i) {
        const int sp = (p0 + i) & 15;
        __builtin_amdgcn_s_barrier();       // ready i: buf[i&1] complete
        const char* lb = &buf[i & 1][0];
        #pragma unroll
        for (int half = 0; half < 2; ++half) {
            #pragma unroll
            for (int sl = 0; sl < 4; ++sl) {
                bf16x8 aa = *(const bf16x8*)(xrow + sp * KCS
                                             + half * 128 + sl * 32);
                #pragma unroll
                for (int n = 0; n < 4; ++n) {
                    const int q   = n * 16 + c;   // W-row = D col
                    const int swz = (q & 7) << 4;
                    const char* base = lb + q * 1024 + half * 512;
                    f32x4 w0 = *(const f32x4*)(base
                                    + ((sl * 128 + kg * 32) ^ swz));
                    f32x4 w1 = *(const f32x4*)(base
                                    + ((sl * 128 + kg * 32 + 16) ^ swz));
                    bf16x8 bb;
                    bb[0] = f2b(w0[0]); bb[1] = f2b(w0[1]);
                    bb[2] = f2b(w0[2]); bb[3] = f2b(w0[3]);
                    bb[4] = f2b(w1[0]); bb[5] = f2b(w1[1]);
                    bb[6] = f2b(w1[2]); bb[7] = f2b(w1[3]);
                    acc[n] = __builtin_amdgcn_mfma_f32_16x16x32_bf16(
                        aa, bb, acc[n], 0, 0, 0);
                }
            }
        }
        __builtin_amdgcn_s_barrier();       // end i
    }

    // lora tail: 2 K-steps over r=64 per col-subtile
    {
        const ushort* y0 = yb + (size_t)(w * 16 + c) * 64 + kg * 8;
        #pragma unroll
        for (int n = 0; n < 4; ++n) {
            const float* br = Bm + (size_t)(j0 + n * 16 + c) * 64 + kg * 8;
            #pragma unroll
            for (int k = 0; k < 64; k += 32) {
                f32x4 w0 = *(const f32x4*)(br + k);
                f32x4 w1 = *(const f32x4*)(br + k + 4);
                bf16x8 bb;
                bb[0] = f2b(w0[0]); bb[1] = f2b(w0[1]);
                bb[2] = f2b(w0[2]); bb[3] = f2b(w0[3]);
                bb[4] = f2b(w1[0]); bb[5] = f2b(w1[1]);
                bb[6] = f2b(w1[2]); bb[7] = f2b(w1[3]);
                bf16x8 aa = *(const bf16x8*)(y0 + k);
                acc[n] = __builtin_amdgcn_mfma_f32_16x16x32_bf16(
                    aa, bb, acc[n], 0, 0, 0);
            }
        }
    }

    // store: token row = w*16 + kg*4 + r, col = j0 + n*16 + c
    #pragma unroll
    for (int n = 0; n < 4; ++n) {
        float* op = out + j0 + n * 16 + c;
        #pragma unroll
        for (int r = 0; r < 4; ++r)
            op[(size_t)(w * 16 + kg * 4 + r) * 16384] = acc[n][r];
    }
}

extern "C" void kernel_launch(void* const* d_in, const int* in_sizes, int n_in,
                              void* d_out, int out_size, void* d_ws, size_t ws_size,
                              hipStream_t stream) {
    const float* x  = (const float*)d_in[0];
    const float* W  = (const float*)d_in[1];
    const float* A  = (const float*)d_in[2];
    const float* Bm = (const float*)d_in[3];
    float* out = (float*)d_out;

    ushort* xb = (ushort*)d_ws;                          // 64*4096*2 = 524288 B
    ushort* yb = (ushort*)((char*)d_ws + 524288);        // 64*64*2   = 8192 B

    prep_kernel<<<1024, 256, 0, stream>>>(x, A, xb, yb);
    lora_gemm<<<256, 512, 0, stream>>>(W, Bm, xb, yb, out);
}